// Round 6
// baseline (1151.159 us; speedup 1.0000x reference)
//
#include <hip/hip_runtime.h>

// NeuralVoxelHash — round 6: TRANSPOSED cooperative gather (1 request/line).
//
// r0-r5 established: L2-fill rate clamps at 3.4-3.55 TB/s across occupancy
// 31-54%, ILP 8-32, nt/cached, phased/fused, sorted/unsorted; bytes are at
// the distinct-line floor. Last untested lever: halve the REQUEST count per
// line. Per-thread layout needs 2 insts per 32B feature row (2 tag lookups
// on the same line) + 8 idx lookups. Transposed layout: lane = (point<<4 |
// corner<<1 | half): both halves of a row are adjacent lanes of ONE
// instruction -> coalescer merges to one line request; idx half-pairs merge
// too. 72 -> 48 distinct-line requests per point (x1.5).
//  - 3 levels fused; level-sum folded BEFORE the corner reduction (linear),
//    so one ds_swizzle xor-tree (lane bits 1..3) per step; no out-RMW.
//  - Hand software pipeline, groups of 2 steps (6 idx + 6 feat asm loads);
//    vmcnt stream contains ONLY these loads (results staged in LDS, stores
//    after the pipeline): W6/W12 counted waits + sched_barrier(0) (rule 18).
//  - Morton sort kept (r5: -12% fills); unpermute folded into final store.

constexpr int       BUF   = 5000000;
constexpr long long NFEAT = 4194304;
constexpr int       DIM   = 8;
constexpr long long P0 = 73856093, P1 = 19349669, P2 = 83492791;
constexpr int       P0m = 3856093, P1m = 4349669, P2m = 3492791;  // P % BUF
constexpr int       NBINS = 1 << 21;   // 7 bits/axis Morton

typedef float vf4 __attribute__((ext_vector_type(4)));

// ---------------- fused transposed kernel -----------------------------------
__global__ __launch_bounds__(256, 4) void nvh_fused(
    const float* __restrict__ qps,     // sorted points [n,3] (or raw if !perm)
    const float* __restrict__ feats,
    const int* __restrict__ idx_tab,
    const unsigned* __restrict__ perm, // sorted slot -> original index (or null)
    float* __restrict__ out, int n)
{
    __shared__ float rec[256 * 12];    // per point: 3 x {k0,dx,dy,dz} (48B)
    __shared__ float res[256 * 8];     // per point: 8 floats result

    const int t    = threadIdx.x;
    const int i    = blockIdx.x * 256 + t;
    const int lane = t & 63;
    const int wbase = t & 192;         // first point of this wave (block-local)

    // ---- pre-phase: per-thread hash state for its own point, all 3 levels.
    unsigned my_perm = (unsigned)i;
    {
        float px = 0.0f, py = 0.0f, pz = 0.0f;
        if (i < n) {
            px = qps[3 * i + 0];
            py = qps[3 * i + 1];
            pz = qps[3 * i + 2];
            if (perm) my_perm = perm[i];
        }
        const float resv[3] = {0.3f, 0.6f, 1.2f};
#pragma unroll
        for (int l = 0; l < 3; ++l) {
            const float res_ = resv[l];
            // IEEE f32 division to match JAX (floor boundary sensitivity)
            const float fx = px / res_, fy = py / res_, fz = pz / res_;
            const float bx = floorf(fx), by = floorf(fy), bz = floorf(fz);
            const long long ix = (long long)bx;
            const long long iy = (long long)by;
            const long long iz = (long long)bz;
            long long h0 = (ix * P0 + iy * P1 + iz * P2) % (long long)BUF;
            if (h0 < 0) h0 += BUF;
            rec[t * 12 + l * 4 + 0] = __int_as_float((int)h0);
            rec[t * 12 + l * 4 + 1] = fx - bx;
            rec[t * 12 + l * 4 + 2] = fy - by;
            rec[t * 12 + l * 4 + 3] = fz - bz;
        }
    }
    __syncthreads();
    // drain pre-phase VMEM so hand vmcnt counts below are exact
    asm volatile("s_waitcnt vmcnt(0)" ::: "memory");
    __builtin_amdgcn_sched_barrier(0);

    // per-lane role: point-sub = lane>>4, corner bits, half
    const bool sx = (lane & 8) != 0;   // corner x-bit (P0 / dx)
    const bool sy = (lane & 4) != 0;   // corner y-bit (P1 / dy)
    const bool sz = (lane & 2) != 0;   // corner z-bit (P2 / dz)
    const unsigned hoff = (unsigned)(lane & 1) * 16u;

    int   idxv[8][6];
    float okv[8][6];
    vf4   fv[8][6];

    // K(g): keys + issue 6 idx loads.  F(g): validity + issue 6 feat loads.
    // M(g): weights, 3-level sum, xor-reduce over corners, stage to LDS.
#define KG(g)                                                                 \
    do {                                                                      \
        _Pragma("unroll") for (int sub = 0; sub < 2; ++sub) {                 \
            const int s_ = 2 * (g) + sub;                                     \
            const int pl_ = wbase + s_ * 4 + (lane >> 4);                     \
            const int rb_ = pl_ * 12;                                         \
            _Pragma("unroll") for (int l = 0; l < 3; ++l) {                   \
                int key = __float_as_int(rec[rb_ + l * 4]);                   \
                if (sx) { key += P0m; if (key >= BUF) key -= BUF; }           \
                if (sy) { key += P1m; if (key >= BUF) key -= BUF; }           \
                if (sz) { key += P2m; if (key >= BUF) key -= BUF; }           \
                const unsigned ko_ = (unsigned)key * 4u;                      \
                asm volatile("global_load_dword %0, %1, %2"                   \
                             : "=v"(idxv[(g)][sub * 3 + l])                   \
                             : "v"(ko_), "s"(idx_tab + (size_t)l * BUF));     \
            }                                                                 \
        }                                                                     \
    } while (0)

#define FG(g)                                                                 \
    do {                                                                      \
        _Pragma("unroll") for (int sub = 0; sub < 2; ++sub) {                 \
            _Pragma("unroll") for (int l = 0; l < 3; ++l) {                   \
                int id_ = idxv[(g)][sub * 3 + l];                             \
                const unsigned long long bal_ = __ballot(id_ > -1);           \
                okv[(g)][sub * 3 + l] =                                       \
                    (((bal_ >> (lane & 48)) & 0xFFFFull) == 0xFFFFull)        \
                        ? 1.0f : 0.0f;                                        \
                id_ = id_ > 0 ? id_ : 0;                                      \
                const unsigned vo_ = (unsigned)id_ * 32u + hoff;              \
                asm volatile("global_load_dwordx4 %0, %1, %2"                 \
                             : "=v"(fv[(g)][sub * 3 + l])                     \
                             : "v"(vo_),                                      \
                               "s"(feats + (size_t)l * NFEAT * DIM));         \
            }                                                                 \
        }                                                                     \
    } while (0)

#define MG(g)                                                                 \
    do {                                                                      \
        _Pragma("unroll") for (int sub = 0; sub < 2; ++sub) {                 \
            const int s_ = 2 * (g) + sub;                                     \
            const int pl_ = wbase + s_ * 4 + (lane >> 4);                     \
            const int rb_ = pl_ * 12;                                         \
            vf4 r_ = (vf4)0.0f;                                               \
            _Pragma("unroll") for (int l = 0; l < 3; ++l) {                   \
                const float dx_ = rec[rb_ + l * 4 + 1];                       \
                const float dy_ = rec[rb_ + l * 4 + 2];                       \
                const float dz_ = rec[rb_ + l * 4 + 3];                       \
                const float w_ = (sx ? dx_ : 1.0f - dx_) *                    \
                                 (sy ? dy_ : 1.0f - dy_) *                    \
                                 (sz ? dz_ : 1.0f - dz_) *                    \
                                 okv[(g)][sub * 3 + l];                       \
                r_ += w_ * fv[(g)][sub * 3 + l];                              \
            }                                                                 \
            vf4 t_;                                                           \
            _Pragma("unroll") for (int e = 0; e < 4; ++e)                     \
                t_[e] = __int_as_float(__builtin_amdgcn_ds_swizzle(           \
                    __float_as_int(r_[e]), 0x081F));                          \
            r_ += t_;                                                         \
            _Pragma("unroll") for (int e = 0; e < 4; ++e)                     \
                t_[e] = __int_as_float(__builtin_amdgcn_ds_swizzle(           \
                    __float_as_int(r_[e]), 0x101F));                          \
            r_ += t_;                                                         \
            _Pragma("unroll") for (int e = 0; e < 4; ++e)                     \
                t_[e] = __int_as_float(__builtin_amdgcn_ds_swizzle(           \
                    __float_as_int(r_[e]), 0x201F));                          \
            r_ += t_;                                                         \
            if ((lane & 14) == 0) {                                           \
                *(vf4*)&res[pl_ * 8 + (lane & 1) * 4] = r_;                   \
            }                                                                 \
        }                                                                     \
    } while (0)

#define VMW(N)                                                                \
    do {                                                                      \
        asm volatile("s_waitcnt vmcnt(" #N ")" ::: "memory");                 \
        __builtin_amdgcn_sched_barrier(0);                                    \
    } while (0)

    // hand-counted pipeline: tokens of 6 loads; idx 2 groups ahead, feat 1.
    KG(0); KG(1);
    VMW(6);  FG(0); KG(2);
    VMW(12); FG(1);
    VMW(12); MG(0);
    KG(3);  VMW(12); FG(2); VMW(12); MG(1);
    KG(4);  VMW(12); FG(3); VMW(12); MG(2);
    KG(5);  VMW(12); FG(4); VMW(12); MG(3);
    KG(6);  VMW(12); FG(5); VMW(12); MG(4);
    KG(7);  VMW(12); FG(6); VMW(12); MG(5);
    VMW(6);  FG(7);
    VMW(6);  MG(6);
    VMW(0);  MG(7);

#undef KG
#undef FG
#undef MG
#undef VMW

    __syncthreads();
    if (i < n) {
        const vf4 a = *(vf4*)&res[t * 8 + 0];
        const vf4 b = *(vf4*)&res[t * 8 + 4];
        float* op = out + (size_t)my_perm * DIM;
        *(vf4*)(op + 0) = a;
        *(vf4*)(op + 4) = b;
    }
}

// ---------------- sort machinery (r5, minus invp/unpermute) -----------------
__device__ __forceinline__ unsigned spread3(unsigned v) {
    v = (v | (v << 16)) & 0x030000FFu;
    v = (v | (v << 8))  & 0x0300F00Fu;
    v = (v | (v << 4))  & 0x030C30C3u;
    v = (v | (v << 2))  & 0x09249249u;
    return v;
}

__global__ __launch_bounds__(256) void zero_hist(unsigned* __restrict__ h) {
    int i = blockIdx.x * blockDim.x + threadIdx.x;
    for (int k = i; k < NBINS; k += gridDim.x * blockDim.x) h[k] = 0u;
}

__global__ __launch_bounds__(256) void keys_hist(
    const float* __restrict__ qp, unsigned* __restrict__ keys,
    unsigned* __restrict__ hist, int n)
{
    int i = blockIdx.x * blockDim.x + threadIdx.x;
    if (i >= n) return;
    const float inv = 1.0f / 1.2f;
    int cx = (int)floorf(qp[3 * i + 0] * inv);
    int cy = (int)floorf(qp[3 * i + 1] * inv);
    int cz = (int)floorf(qp[3 * i + 2] * inv);
    cx = cx < -64 ? -64 : (cx > 63 ? 63 : cx);
    cy = cy < -64 ? -64 : (cy > 63 ? 63 : cy);
    cz = cz < -64 ? -64 : (cz > 63 ? 63 : cz);
    const unsigned key = (spread3((unsigned)(cx + 64)) << 2) |
                         (spread3((unsigned)(cy + 64)) << 1) |
                          spread3((unsigned)(cz + 64));
    keys[i] = key;
    atomicAdd(&hist[key], 1u);
}

__global__ __launch_bounds__(256) void scan_blocks(
    unsigned* __restrict__ data, unsigned* __restrict__ bsum)
{
    __shared__ unsigned s[256];
    const int t = threadIdx.x;
    const int base = blockIdx.x * 1024 + t * 4;
    unsigned v0 = data[base + 0], v1 = data[base + 1];
    unsigned v2 = data[base + 2], v3 = data[base + 3];
    const unsigned tsum = v0 + v1 + v2 + v3;
    s[t] = tsum;
    __syncthreads();
    for (int off = 1; off < 256; off <<= 1) {
        unsigned x = (t >= off) ? s[t - off] : 0u;
        __syncthreads();
        s[t] += x;
        __syncthreads();
    }
    const unsigned excl = s[t] - tsum;
    if (t == 255) bsum[blockIdx.x] = s[255];
    data[base + 0] = excl;
    data[base + 1] = excl + v0;
    data[base + 2] = excl + v0 + v1;
    data[base + 3] = excl + v0 + v1 + v2;
}

__global__ __launch_bounds__(256) void scan_top(unsigned* __restrict__ bsum) {
    __shared__ unsigned s[256];
    const int t = threadIdx.x;
    unsigned v[8];
    unsigned tsum = 0;
#pragma unroll
    for (int j = 0; j < 8; ++j) { v[j] = bsum[t * 8 + j]; tsum += v[j]; }
    s[t] = tsum;
    __syncthreads();
    for (int off = 1; off < 256; off <<= 1) {
        unsigned x = (t >= off) ? s[t - off] : 0u;
        __syncthreads();
        s[t] += x;
        __syncthreads();
    }
    unsigned run = s[t] - tsum;
#pragma unroll
    for (int j = 0; j < 8; ++j) { const unsigned nv = run; run += v[j]; bsum[t * 8 + j] = nv; }
}

__global__ __launch_bounds__(256) void scan_add(
    unsigned* __restrict__ data, const unsigned* __restrict__ bsum)
{
    const int base = blockIdx.x * 1024 + threadIdx.x * 4;
    const unsigned add = bsum[blockIdx.x];
    data[base + 0] += add;
    data[base + 1] += add;
    data[base + 2] += add;
    data[base + 3] += add;
}

__global__ __launch_bounds__(256) void scatter_perm(
    const unsigned* __restrict__ keys, unsigned* __restrict__ hist,
    unsigned* __restrict__ perm, int n)
{
    int i = blockIdx.x * blockDim.x + threadIdx.x;
    if (i >= n) return;
    const unsigned r = atomicAdd(&hist[keys[i]], 1u);
    perm[r] = (unsigned)i;
}

__global__ __launch_bounds__(256) void gather_points(
    const float* __restrict__ qp, const unsigned* __restrict__ perm,
    float* __restrict__ qps, int n)
{
    int i = blockIdx.x * blockDim.x + threadIdx.x;
    if (i >= n) return;
    const unsigned j = perm[i];
    qps[3 * i + 0] = qp[3 * j + 0];
    qps[3 * i + 1] = qp[3 * j + 1];
    qps[3 * i + 2] = qp[3 * j + 2];
}

// ---------------- launch ----------------------------------------------------
extern "C" void kernel_launch(void* const* d_in, const int* in_sizes, int n_in,
                              void* d_out, int out_size, void* d_ws, size_t ws_size,
                              hipStream_t stream) {
    const float* qp      = (const float*)d_in[0];
    const float* feats   = (const float*)d_in[1];
    const int*   idx_tab = (const int*)d_in[2];
    float*       out     = (float*)d_out;

    const int n = in_sizes[0] / 3;
    const int block = 256;
    const int grid = (n + block - 1) / block;

    auto al = [](size_t x) { return (x + 255) & ~(size_t)255; };
    const size_t o_hist = 0;
    const size_t o_bsum = al(o_hist + (size_t)NBINS * 4);
    const size_t o_keys = al(o_bsum + 2048 * 4);
    const size_t o_perm = al(o_keys + (size_t)n * 4);
    const size_t o_qps  = al(o_perm + (size_t)n * 4);
    const size_t need   = o_qps + (size_t)n * 12;

    const bool use_sort = (d_ws != nullptr) && (ws_size >= need);

    if (use_sort) {
        char* ws = (char*)d_ws;
        unsigned* hist = (unsigned*)(ws + o_hist);
        unsigned* bsum = (unsigned*)(ws + o_bsum);
        unsigned* keys = (unsigned*)(ws + o_keys);
        unsigned* perm = (unsigned*)(ws + o_perm);
        float*    qps  = (float*)   (ws + o_qps);

        hipLaunchKernelGGL(zero_hist, dim3(2048), dim3(block), 0, stream, hist);
        hipLaunchKernelGGL(keys_hist, dim3(grid), dim3(block), 0, stream,
                           qp, keys, hist, n);
        hipLaunchKernelGGL(scan_blocks, dim3(NBINS / 1024), dim3(block), 0,
                           stream, hist, bsum);
        hipLaunchKernelGGL(scan_top, dim3(1), dim3(block), 0, stream, bsum);
        hipLaunchKernelGGL(scan_add, dim3(NBINS / 1024), dim3(block), 0,
                           stream, hist, bsum);
        hipLaunchKernelGGL(scatter_perm, dim3(grid), dim3(block), 0, stream,
                           keys, hist, perm, n);
        hipLaunchKernelGGL(gather_points, dim3(grid), dim3(block), 0, stream,
                           qp, perm, qps, n);
        hipLaunchKernelGGL(nvh_fused, dim3(grid), dim3(block), 0, stream,
                           qps, feats, idx_tab, perm, out, n);
    } else {
        hipLaunchKernelGGL(nvh_fused, dim3(grid), dim3(block), 0, stream,
                           qp, feats, idx_tab, (const unsigned*)nullptr, out, n);
    }
}